// Round 5
// baseline (19.862 us; speedup 1.0000x reference)
//
#include <hip/hip_runtime.h>

// Sizes fixed by the reference: B=512, H=1024, D=5, 32 multivector comps.
#define NB 512
#define NH 1024
#define ND 5
#define NCH 32              // h-chunks for T partials
#define CH (NH / NCH)       // 32 h per chunk
#define NPROD (ND * NCH)    // 160 producer blocks
#define NCONS (NB / 8)      // 64 consumer blocks
// 1 - (1-dt)^N_FREE = 1 - 0.9^10
#define SCALE 0.6513215599f
// Quiet-NaN bit pattern: can never equal a finite float or the 0xAA poison.
#define MAGIC 0x7FC0DEADu

// Cayley sign for Cl(4,1), metric diag(1,1,1,1,-1): e_a*e_b = sign(a,b)*e_{a^b}
__device__ __forceinline__ float cl_sign(int a, int b) {
    int cnt = 0;
    int aa = a >> 1;
    while (aa) { cnt += __popc(aa & b); aa >>= 1; }
    float s = (cnt & 1) ? -1.0f : 1.0f;
    if ((a & b) & 16) s = -s;   // e5*e5 = -1 (bit 4)
    return s;
}

// Single fused kernel: blocks [0,160) produce partial T, blocks [160,224) consume.
// Tp layout: [hc][d*32+m] (32 x 160 floats in ws), flags: 160 uints after Tp.
__global__ __launch_bounds__(256, 1) void k_fused(
        const float* __restrict__ x, const float* __restrict__ Win,
        const float* __restrict__ Wout, float* __restrict__ Tp,
        unsigned int* __restrict__ flags, float* __restrict__ out) {
    const int t = threadIdx.x;
    if (blockIdx.x < NPROD) {
        // ---------------- producer: partial G over h-chunk -> partial T ----
        __shared__ __align__(16) float as[CH][32];
        __shared__ __align__(16) float bs[CH][32];
        __shared__ float gs[1024];
        __shared__ float red[8][32];
        const int d = blockIdx.x >> 5, hc = blockIdx.x & 31, h0 = hc * CH;
        {
            const int row = t >> 3;            // 0..31
            const int c4  = (t & 7) * 4;       // 0,4,...,28
            const int h = h0 + row;
            *(float4*)&as[row][c4] = *(const float4*)&Win[h * (ND * 32) + d * 32 + c4];
            *(float4*)&bs[row][c4] = *(const float4*)&Wout[h * 32 + c4];
        }
        __syncthreads();
        const int s0 = (t >> 4) << 1;
        const int q0 = (t & 15) << 1;
        float a00 = 0.f, a01 = 0.f, a10 = 0.f, a11 = 0.f;
        #pragma unroll
        for (int h = 0; h < CH; ++h) {
            const float2 av = *(const float2*)&as[h][s0];
            const float2 bv = *(const float2*)&bs[h][q0];
            a00 += av.x * bv.x; a01 += av.x * bv.y;
            a10 += av.y * bv.x; a11 += av.y * bv.y;
        }
        gs[s0 * 32 + q0]           = a00;
        gs[s0 * 32 + q0 + 1]       = a01;
        gs[(s0 + 1) * 32 + q0]     = a10;
        gs[(s0 + 1) * 32 + q0 + 1] = a11;
        __syncthreads();
        // collapse: partial T[m] = sum_s sign(s,s^m)*gs[s*32 + (s^m)]
        const int m = t & 31, grp = t >> 5;
        float acc = 0.f;
        #pragma unroll
        for (int j = 0; j < 4; ++j) {
            const int s = grp * 4 + j;
            acc += cl_sign(s, s ^ m) * gs[s * 32 + (s ^ m)];
        }
        red[grp][m] = acc;
        __syncthreads();
        if (t < 32) {
            float sum = 0.f;
            #pragma unroll
            for (int c = 0; c < 8; ++c) sum += red[c][t];
            __hip_atomic_store(&Tp[hc * (ND * 32) + d * 32 + t], sum,
                               __ATOMIC_RELAXED, __HIP_MEMORY_SCOPE_AGENT);
        }
        __syncthreads();       // drains vmcnt for the whole block
        __threadfence();       // device-scope visibility of Tp before flag
        if (t == 0)
            __hip_atomic_store(&flags[blockIdx.x], MAGIC,
                               __ATOMIC_RELEASE, __HIP_MEMORY_SCOPE_AGENT);
    } else {
        // ---------------- consumer: pred for 8 batch rows ------------------
        __shared__ float Tl[ND * 32];
        __shared__ float sgn[1024];
        __shared__ __align__(16) float ks[ND * 1024];
        __shared__ __align__(16) float xs[8 * ND * 32];
        const int b0 = (blockIdx.x - NPROD) * 8;
        // pre-spin work: stage x and the (scaled) sign table
        for (int i = t; i < 8 * ND * 32 / 4; i += 256)
            ((float4*)xs)[i] = ((const float4*)&x[b0 * (ND * 32)])[i];
        #pragma unroll
        for (int j = 0; j < 4; ++j) {
            const int i = j * 256 + t;
            const int r = i >> 5, k = i & 31;
            sgn[i] = SCALE * cl_sign(r, r ^ k);
        }
        // wait for all producers
        int done;
        do {
            done = (t < NPROD)
                 ? (__hip_atomic_load(&flags[t], __ATOMIC_ACQUIRE,
                                      __HIP_MEMORY_SCOPE_AGENT) == MAGIC)
                 : 1;
        } while (!__syncthreads_and(done));
        // reduce the 32 partial-T slabs (uncached agent loads, independent)
        if (t < ND * 32) {
            float s = 0.f;
            #pragma unroll
            for (int hc = 0; hc < NCH; ++hc)
                s += __hip_atomic_load(&Tp[hc * (ND * 32) + t], __ATOMIC_RELAXED,
                                       __HIP_MEMORY_SCOPE_AGENT);
            Tl[t] = s;
        }
        __syncthreads();
        // expand K[d,r,k] = sgn[r,k] * T[d, r^k] into LDS
        #pragma unroll
        for (int j = 0; j < ND * 1024 / 256; ++j) {
            const int i = j * 256 + t;
            const int d = i >> 10, rk = i & 1023, r = (i >> 5) & 31, k = i & 31;
            ks[i] = sgn[rk] * Tl[d * 32 + (r ^ k)];
        }
        __syncthreads();
        const int bl = t >> 5, k = t & 31;
        float acc = 0.f;
        #pragma unroll
        for (int d = 0; d < ND; ++d) {
            #pragma unroll
            for (int r4 = 0; r4 < 8; ++r4) {
                const float4 xv = *(const float4*)&xs[bl * 160 + d * 32 + r4 * 4];
                acc += xv.x * ks[d * 1024 + (r4 * 4 + 0) * 32 + k];
                acc += xv.y * ks[d * 1024 + (r4 * 4 + 1) * 32 + k];
                acc += xv.z * ks[d * 1024 + (r4 * 4 + 2) * 32 + k];
                acc += xv.w * ks[d * 1024 + (r4 * 4 + 3) * 32 + k];
            }
        }
        out[(b0 + bl) * 32 + k] = acc;
    }
}

extern "C" void kernel_launch(void* const* d_in, const int* in_sizes, int n_in,
                              void* d_out, int out_size, void* d_ws, size_t ws_size,
                              hipStream_t stream) {
    const float* x_mv  = (const float*)d_in[0];   // (512, 5, 32)
    const float* W_in  = (const float*)d_in[1];   // (1024, 5, 32)
    const float* W_out = (const float*)d_in[2];   // (1, 1024, 32)
    float* out = (float*)d_out;                   // (512, 1, 32)

    float* Tp = (float*)d_ws;                     // NCH*ND*32 floats (20 KB)
    unsigned int* flags = (unsigned int*)(Tp + NCH * ND * 32);  // 160 uints

    k_fused<<<NPROD + NCONS, 256, 0, stream>>>(x_mv, W_in, W_out, Tp, flags, out);
}

// Round 6
// 10.693 us; speedup vs baseline: 1.8575x; 1.8575x over previous
//
#include <hip/hip_runtime.h>

// Sizes fixed by the reference: B=512, H=1024, D=5, 32 multivector comps.
#define NB 512
#define NH 1024
#define ND 5
#define NCH 8               // h-chunks for T partials
#define CH (NH / NCH)       // 128 h per chunk
#define NPROD (ND * NCH)    // 40 producer blocks
#define NCONS (NB / 8)      // 64 consumer blocks
// 1 - (1-dt)^N_FREE = 1 - 0.9^10
#define SCALE 0.6513215599f
// Quiet-NaN bit pattern: never equals a finite float or the 0xAA poison.
#define MAGIC 0x7FC0DEADu

// Cayley sign for Cl(4,1), metric diag(1,1,1,1,-1): e_a*e_b = sign(a,b)*e_{a^b}
__device__ __forceinline__ float cl_sign(int a, int b) {
    int cnt = 0;
    int aa = a >> 1;
    while (aa) { cnt += __popc(aa & b); aa >>= 1; }
    float s = (cnt & 1) ? -1.0f : 1.0f;
    if ((a & b) & 16) s = -s;   // e5*e5 = -1 (bit 4)
    return s;
}

// Single fused kernel: blocks [0,40) produce partial T, blocks [40,104) consume.
// Tp layout: [hc][d*32+m] (8 x 160 floats), flags: 40 uints after Tp.
__global__ __launch_bounds__(256, 1) void k_fused(
        const float* __restrict__ x, const float* __restrict__ Win,
        const float* __restrict__ Wout, float* __restrict__ Tp,
        unsigned int* __restrict__ flags, float* __restrict__ out) {
    __shared__ __align__(16) char smem[38912];
    const int t = threadIdx.x;
    if (blockIdx.x < NPROD) {
        // ---------------- producer: partial G over h-chunk -> partial T ----
        float (*as)[32] = (float(*)[32])(smem);            // 16384 B
        float (*bs)[32] = (float(*)[32])(smem + 16384);    // 16384 B
        float* gs       = (float*)(smem + 32768);          // 4096 B
        float (*red)[32]= (float(*)[32])(smem + 36864);    // 1024 B
        const int d = blockIdx.x >> 3, hc = blockIdx.x & 7, h0 = hc * CH;
        {
            const int row = t >> 3;            // 0..31
            const int c4  = (t & 7) * 4;       // 0,4,...,28
            #pragma unroll
            for (int j = 0; j < 4; ++j) {
                const int h = h0 + row + j * 32;
                *(float4*)&as[row + j * 32][c4] = *(const float4*)&Win[h * (ND * 32) + d * 32 + c4];
                *(float4*)&bs[row + j * 32][c4] = *(const float4*)&Wout[h * 32 + c4];
            }
        }
        __syncthreads();
        const int s0 = (t >> 4) << 1;
        const int q0 = (t & 15) << 1;
        float a00 = 0.f, a01 = 0.f, a10 = 0.f, a11 = 0.f;
        #pragma unroll
        for (int h = 0; h < CH; ++h) {
            const float2 av = *(const float2*)&as[h][s0];
            const float2 bv = *(const float2*)&bs[h][q0];
            a00 += av.x * bv.x; a01 += av.x * bv.y;
            a10 += av.y * bv.x; a11 += av.y * bv.y;
        }
        gs[s0 * 32 + q0]           = a00;
        gs[s0 * 32 + q0 + 1]       = a01;
        gs[(s0 + 1) * 32 + q0]     = a10;
        gs[(s0 + 1) * 32 + q0 + 1] = a11;
        __syncthreads();
        // collapse: partial T[m] = sum_s sign(s,s^m)*gs[s*32 + (s^m)]
        const int m = t & 31, grp = t >> 5;
        float acc = 0.f;
        #pragma unroll
        for (int j = 0; j < 4; ++j) {
            const int s = grp * 4 + j;
            acc += cl_sign(s, s ^ m) * gs[s * 32 + (s ^ m)];
        }
        red[grp][m] = acc;
        __syncthreads();
        if (t < 32) {
            float sum = 0.f;
            #pragma unroll
            for (int c = 0; c < 8; ++c) sum += red[c][t];
            __hip_atomic_store(&Tp[hc * (ND * 32) + d * 32 + t], sum,
                               __ATOMIC_RELAXED, __HIP_MEMORY_SCOPE_AGENT);
        }
        __syncthreads();       // all Tp stores issued before the flag
        if (t == 0)
            __hip_atomic_store(&flags[blockIdx.x], MAGIC,
                               __ATOMIC_RELEASE, __HIP_MEMORY_SCOPE_AGENT);
    } else {
        // ---------------- consumer: pred for 8 batch rows ------------------
        float* Tl  = (float*)(smem);            // 640 B (pad to 1024)
        float* sgn = (float*)(smem + 1024);     // 4096 B
        float* ks  = (float*)(smem + 5120);     // 20480 B
        float* xs  = (float*)(smem + 25600);    // 5120 B
        const int b0 = (blockIdx.x - NPROD) * 8;
        // pre-spin work: stage x and the (scaled) sign table
        for (int i = t; i < 8 * ND * 32 / 4; i += 256)
            ((float4*)xs)[i] = ((const float4*)&x[b0 * (ND * 32)])[i];
        #pragma unroll
        for (int j = 0; j < 4; ++j) {
            const int i = j * 256 + t;
            const int r = i >> 5, k = i & 31;
            sgn[i] = SCALE * cl_sign(r, r ^ k);
        }
        // wait for all producers (polite spin: 40 lanes, s_sleep backoff)
        for (;;) {
            const int mine = (t < NPROD)
                ? (__hip_atomic_load(&flags[t], __ATOMIC_ACQUIRE,
                                     __HIP_MEMORY_SCOPE_AGENT) == MAGIC)
                : 1;
            if (__syncthreads_and(mine)) break;
            __builtin_amdgcn_s_sleep(16);
        }
        // reduce the 8 partial-T slabs
        if (t < ND * 32) {
            float s = 0.f;
            #pragma unroll
            for (int hc = 0; hc < NCH; ++hc)
                s += __hip_atomic_load(&Tp[hc * (ND * 32) + t], __ATOMIC_RELAXED,
                                       __HIP_MEMORY_SCOPE_AGENT);
            Tl[t] = s;
        }
        __syncthreads();
        // expand K[d,r,k] = sgn[r,k] * T[d, r^k] into LDS
        #pragma unroll
        for (int j = 0; j < ND * 1024 / 256; ++j) {
            const int i = j * 256 + t;
            const int d = i >> 10, rk = i & 1023, r = (i >> 5) & 31, k = i & 31;
            ks[i] = sgn[rk] * Tl[d * 32 + (r ^ k)];
        }
        __syncthreads();
        const int bl = t >> 5, k = t & 31;
        float acc = 0.f;
        #pragma unroll
        for (int d = 0; d < ND; ++d) {
            #pragma unroll
            for (int r4 = 0; r4 < 8; ++r4) {
                const float4 xv = *(const float4*)&xs[bl * 160 + d * 32 + r4 * 4];
                acc += xv.x * ks[d * 1024 + (r4 * 4 + 0) * 32 + k];
                acc += xv.y * ks[d * 1024 + (r4 * 4 + 1) * 32 + k];
                acc += xv.z * ks[d * 1024 + (r4 * 4 + 2) * 32 + k];
                acc += xv.w * ks[d * 1024 + (r4 * 4 + 3) * 32 + k];
            }
        }
        out[(b0 + bl) * 32 + k] = acc;
    }
}

extern "C" void kernel_launch(void* const* d_in, const int* in_sizes, int n_in,
                              void* d_out, int out_size, void* d_ws, size_t ws_size,
                              hipStream_t stream) {
    const float* x_mv  = (const float*)d_in[0];   // (512, 5, 32)
    const float* W_in  = (const float*)d_in[1];   // (1024, 5, 32)
    const float* W_out = (const float*)d_in[2];   // (1, 1024, 32)
    float* out = (float*)d_out;                   // (512, 1, 32)

    float* Tp = (float*)d_ws;                                   // 8*160 floats
    unsigned int* flags = (unsigned int*)(Tp + NCH * ND * 32);  // 40 uints

    k_fused<<<NPROD + NCONS, 256, 0, stream>>>(x_mv, W_in, W_out, Tp, flags, out);
}